// Round 2
// baseline (256.606 us; speedup 1.0000x reference)
//
#include <hip/hip_runtime.h>
#include <hip/hip_bf16.h>

#define N_TOT   32768
#define NUMNODE 128
#define NGRAPH  256
#define EDGES   524288
#define HDIM    128
#define MLP_HID 512
#define OUTDIM  10
#define KBIG    16384   // NUMNODE*HDIM

typedef __attribute__((ext_vector_type(8))) short  short8;   // 8 x bf16 bits
typedef __attribute__((ext_vector_type(4))) float  floatx4;  // MFMA accumulator

#define MFMA(a,b,c) __builtin_amdgcn_mfma_f32_16x16x32_bf16((a),(b),(c),0,0,0)

__device__ __forceinline__ unsigned short f2b(float f){
  __hip_bfloat16 h = __float2bfloat16(f);
  union { __hip_bfloat16 h; unsigned short u; } cv; cv.h = h; return cv.u;
}

// ---- degree count (target side, like reference col aggregation) ----
__global__ __launch_bounds__(256) void k_fill(const int* __restrict__ ei,
                                              int* __restrict__ cnt){
  int e = blockIdx.x*256 + threadIdx.x;
  int d = ei[EDGES + e];
  atomicAdd(&cnt[d], 1);
}

// ---- dinv = rsqrt(deg + self-loop) ----
__global__ __launch_bounds__(256) void k_dinv(const int* __restrict__ cnt,
                                              float* __restrict__ dinv){
  int i = blockIdx.x*256 + threadIdx.x;
  dinv[i] = rsqrtf((float)(cnt[i] + 1));
}

// ---- scatter normalized adjacency: adjf[g][dst][src] += dinv[d]*dinv[s] ----
__global__ __launch_bounds__(256) void k_adj(const int* __restrict__ ei,
                                             const float* __restrict__ dinv,
                                             float* __restrict__ adjf){
  int e = blockIdx.x*256 + threadIdx.x;
  int s = ei[e];
  int d = ei[EDGES + e];
  int g = d >> 7;
  atomicAdd(&adjf[(size_t)g*16384 + (d & 127)*128 + (s & 127)],
            dinv[d]*dinv[s]);
}

// ---- add self-loop diag, cast adjacency to bf16 ----
__global__ __launch_bounds__(256) void k_adjcast(const float* __restrict__ adjf,
                                                 const float* __restrict__ dinv,
                                                 unsigned short* __restrict__ adjb){
  int idx = blockIdx.x*256 + threadIdx.x;      // over 4194304/4
  float4 v = ((const float4*)adjf)[idx];
  int cell = idx*4;
  int node = cell >> 7;                        // = g*128 + d
  int d = (cell >> 7) & 127, s0 = cell & 127;
  int dd = d - s0;
  if (dd >= 0 && dd < 4){
    float dv = dinv[node];
    if (dd == 0) v.x += dv*dv;
    else if (dd == 1) v.y += dv*dv;
    else if (dd == 2) v.z += dv*dv;
    else v.w += dv*dv;
  }
  ushort4 o; o.x=f2b(v.x); o.y=f2b(v.y); o.z=f2b(v.z); o.w=f2b(v.w);
  ((ushort4*)adjb)[idx] = o;
}

// ---- cast x fp32 -> bf16 ----
__global__ __launch_bounds__(256) void k_cast_x(const float* __restrict__ x,
                                                unsigned short* __restrict__ xb){
  int i = blockIdx.x*256 + threadIdx.x;   // 1048576 float4s
  float4 v = ((const float4*)x)[i];
  ushort4 o; o.x=f2b(v.x); o.y=f2b(v.y); o.z=f2b(v.z); o.w=f2b(v.w);
  ((ushort4*)xb)[i] = o;
}

// ---- W1/W2 transpose+cast ----
__global__ __launch_bounds__(256) void k_castT_w(const float* __restrict__ W1,
                                                 const float* __restrict__ W2,
                                                 unsigned short* __restrict__ w1t,
                                                 unsigned short* __restrict__ w2t){
  int idx = blockIdx.x*256 + threadIdx.x;
  int sel = idx >> 14; int i = idx & 16383;
  int k = i >> 7, n = i & 127;
  const float* W = sel ? W2 : W1;
  unsigned short* D = sel ? w2t : w1t;
  D[n*HDIM + k] = f2b(W[k*HDIM + n]);
}

// ---- lin1_w [16384][512] -> transposed bf16 [512][16384] ----
__global__ __launch_bounds__(256) void k_castT_lin1(const float* __restrict__ W,
                                                    unsigned short* __restrict__ WT){
  __shared__ unsigned short tile[32][33];
  int k0 = blockIdx.x*32, n0 = blockIdx.y*32;
  int lx = threadIdx.x & 31, ly = threadIdx.x >> 5;
  #pragma unroll
  for (int i = 0; i < 4; ++i)
    tile[ly + i*8][lx] = f2b(W[(size_t)(k0 + ly + i*8)*MLP_HID + n0 + lx]);
  __syncthreads();
  #pragma unroll
  for (int i = 0; i < 4; ++i)
    WT[(size_t)(n0 + ly + i*8)*KBIG + k0 + lx] = tile[lx][ly + i*8];
}

// ---- feature GEMM: [Mx128]bf16 @ W -> bf16 output TRANSPOSED per graph ----
// out layout: hT[g][feat(128)][node(128)]
__global__ __launch_bounds__(256) void gemm_xw_T(const unsigned short* __restrict__ A,
                                                 const unsigned short* __restrict__ BT,
                                                 unsigned short* __restrict__ CT){
  int wave = threadIdx.x >> 6, lane = threadIdx.x & 63;
  int m0 = blockIdx.x*64 + wave*16;
  int n0 = blockIdx.y*64;
  int r = lane & 15, q = lane >> 4;
  floatx4 z = {0.f,0.f,0.f,0.f};
  floatx4 acc0=z, acc1=z, acc2=z, acc3=z;
  const short8* Ap = (const short8*)(A  + (size_t)(m0 + r)*HDIM + q*8);
  const short8* Bp = (const short8*)(BT + (size_t)(n0 + r)*HDIM + q*8);
  #pragma unroll
  for (int ks = 0; ks < 4; ++ks){
    short8 a = Ap[ks*4];
    acc0 = MFMA(a, Bp[ks*4      ], acc0);
    acc1 = MFMA(a, Bp[ks*4 + 256], acc1);
    acc2 = MFMA(a, Bp[ks*4 + 512], acc2);
    acc3 = MFMA(a, Bp[ks*4 + 768], acc3);
  }
  int g = m0 >> 7;
  int nl = (m0 & 127) + q*4;               // node-local base of this lane's 4 rows
  unsigned short* base = CT + (size_t)g*KBIG + nl;
  ushort4 o;
  o.x=f2b(acc0[0]); o.y=f2b(acc0[1]); o.z=f2b(acc0[2]); o.w=f2b(acc0[3]);
  *(ushort4*)(base + (size_t)(n0 +  0 + r)*NUMNODE) = o;
  o.x=f2b(acc1[0]); o.y=f2b(acc1[1]); o.z=f2b(acc1[2]); o.w=f2b(acc1[3]);
  *(ushort4*)(base + (size_t)(n0 + 16 + r)*NUMNODE) = o;
  o.x=f2b(acc2[0]); o.y=f2b(acc2[1]); o.z=f2b(acc2[2]); o.w=f2b(acc2[3]);
  *(ushort4*)(base + (size_t)(n0 + 32 + r)*NUMNODE) = o;
  o.x=f2b(acc3[0]); o.y=f2b(acc3[1]); o.z=f2b(acc3[2]); o.w=f2b(acc3[3]);
  *(ushort4*)(base + (size_t)(n0 + 48 + r)*NUMNODE) = o;
}

// ---- aggregation GEMM: Anorm[g] @ h[g] + bias, relu -> hact [node][feat] ----
__global__ __launch_bounds__(256) void gemm_adj(const unsigned short* __restrict__ adjb,
                                                const unsigned short* __restrict__ hT,
                                                const float* __restrict__ bias,
                                                unsigned short* __restrict__ hact){
  int wave = threadIdx.x >> 6, lane = threadIdx.x & 63;
  int m0 = blockIdx.x*64 + wave*16;        // global dst node
  int n0 = blockIdx.y*64;                  // feat
  int g = m0 >> 7, ml = m0 & 127;
  int r = lane & 15, q = lane >> 4;
  floatx4 z = {0.f,0.f,0.f,0.f};
  floatx4 acc0=z, acc1=z, acc2=z, acc3=z;
  const short8* Ap = (const short8*)(adjb + (size_t)g*KBIG + (ml + r)*NUMNODE + q*8);
  const short8* Bp = (const short8*)(hT   + (size_t)g*KBIG + (n0 + r)*NUMNODE + q*8);
  #pragma unroll
  for (int ks = 0; ks < 4; ++ks){
    short8 a = Ap[ks*4];
    acc0 = MFMA(a, Bp[ks*4      ], acc0);
    acc1 = MFMA(a, Bp[ks*4 + 256], acc1);
    acc2 = MFMA(a, Bp[ks*4 + 512], acc2);
    acc3 = MFMA(a, Bp[ks*4 + 768], acc3);
  }
  unsigned short* Crow = hact + (size_t)(m0 + q*4)*HDIM;
  float bv0 = bias[n0 +  0 + r], bv1 = bias[n0 + 16 + r];
  float bv2 = bias[n0 + 32 + r], bv3 = bias[n0 + 48 + r];
  #pragma unroll
  for (int rr = 0; rr < 4; ++rr){
    Crow[(size_t)rr*HDIM + n0 +  0 + r] = f2b(fmaxf(acc0[rr] + bv0, 0.f));
    Crow[(size_t)rr*HDIM + n0 + 16 + r] = f2b(fmaxf(acc1[rr] + bv1, 0.f));
    Crow[(size_t)rr*HDIM + n0 + 32 + r] = f2b(fmaxf(acc2[rr] + bv2, 0.f));
    Crow[(size_t)rr*HDIM + n0 + 48 + r] = f2b(fmaxf(acc3[rr] + bv3, 0.f));
  }
}

// ---- lin1: [256 x 16384] @ BT[512][16384], split-K=32, fp32 atomic reduce ----
__global__ __launch_bounds__(256) void gemm_lin1(const unsigned short* __restrict__ A,
                                                 const unsigned short* __restrict__ BT,
                                                 float* __restrict__ C){
  int wave = threadIdx.x >> 6, lane = threadIdx.x & 63;
  int m0 = blockIdx.x*64 + wave*16;
  int n0 = blockIdx.y*64;
  int k0 = blockIdx.z*512;
  int r = lane & 15, q = lane >> 4;
  floatx4 z = {0.f,0.f,0.f,0.f};
  floatx4 acc0=z, acc1=z, acc2=z, acc3=z;
  const short8* Ap = (const short8*)(A  + (size_t)(m0 + r)*KBIG + k0 + q*8);
  const short8* Bp = (const short8*)(BT + (size_t)(n0 + r)*KBIG + k0 + q*8);
  #pragma unroll 4
  for (int ks = 0; ks < 16; ++ks){
    short8 a = Ap[ks*4];
    acc0 = MFMA(a, Bp[ks*4         ], acc0);
    acc1 = MFMA(a, Bp[ks*4 + 32768 ], acc1);
    acc2 = MFMA(a, Bp[ks*4 + 65536 ], acc2);
    acc3 = MFMA(a, Bp[ks*4 + 98304 ], acc3);
  }
  #pragma unroll
  for (int rr = 0; rr < 4; ++rr){
    int row = m0 + q*4 + rr;
    atomicAdd(&C[(size_t)row*MLP_HID + n0 +  0 + r], acc0[rr]);
    atomicAdd(&C[(size_t)row*MLP_HID + n0 + 16 + r], acc1[rr]);
    atomicAdd(&C[(size_t)row*MLP_HID + n0 + 32 + r], acc2[rr]);
    atomicAdd(&C[(size_t)row*MLP_HID + n0 + 48 + r], acc3[rr]);
  }
}

// ---- lin2 with fused bias+relu on h3: [256x512] @ [512x10] + b2 ----
__global__ __launch_bounds__(256) void k_lin2(const float* __restrict__ h3,
                                              const float* __restrict__ b1,
                                              const float* __restrict__ w2,
                                              const float* __restrict__ b2,
                                              float* __restrict__ out){
  int wave = threadIdx.x >> 6, lane = threadIdx.x & 63;
  int m = blockIdx.x*4 + wave;
  float hv[8];
  #pragma unroll
  for (int i = 0; i < 8; ++i)
    hv[i] = fmaxf(h3[(size_t)m*MLP_HID + lane + i*64] + b1[lane + i*64], 0.f);
  #pragma unroll
  for (int j = 0; j < OUTDIM; ++j){
    float p = 0.f;
    #pragma unroll
    for (int i = 0; i < 8; ++i) p += hv[i] * w2[(lane + i*64)*OUTDIM + j];
    #pragma unroll
    for (int off = 32; off > 0; off >>= 1) p += __shfl_down(p, off);
    if (lane == 0) out[m*OUTDIM + j] = p + b2[j];
  }
}

extern "C" void kernel_launch(void* const* d_in, const int* in_sizes, int n_in,
                              void* d_out, int out_size, void* d_ws, size_t ws_size,
                              hipStream_t stream){
  const float* x   = (const float*)d_in[0];
  const int*   ei  = (const int*)d_in[1];
  const float* W1  = (const float*)d_in[3];
  const float* b1  = (const float*)d_in[4];
  const float* W2  = (const float*)d_in[5];
  const float* b2  = (const float*)d_in[6];
  const float* l1w = (const float*)d_in[7];
  const float* l1b = (const float*)d_in[8];
  const float* l2w = (const float*)d_in[9];
  const float* l2b = (const float*)d_in[10];
  float* out = (float*)d_out;

  char* ws = (char*)d_ws;
  // [0, 17432576) zeroed by one memset: cnt | h3 | adjf
  int*            cnt    = (int*)           (ws + 0);          // 128 KB
  float*          h3     = (float*)         (ws + 131072);     // 512 KB
  float*          adjf   = (float*)         (ws + 655360);     // 16 MB (dead after k_adjcast)
  unsigned short* l1wt   = (unsigned short*)(ws + 655360);     // overlays adjf
  float*          dinv   = (float*)         (ws + 17432576);   // 128 KB
  unsigned short* adjb   = (unsigned short*)(ws + 17563648);   // 8 MB
  unsigned short* xb     = (unsigned short*)(ws + 25952256);   // 8 MB
  unsigned short* w1t    = (unsigned short*)(ws + 34340864);   // 32 KB
  unsigned short* w2t    = (unsigned short*)(ws + 34373632);   // 32 KB
  unsigned short* hT     = (unsigned short*)(ws + 34406400);   // 8 MB
  unsigned short* hact   = (unsigned short*)(ws + 42795008);   // 8 MB  (end ~48.8 MB)

  hipMemsetAsync(ws, 0, 17432576, stream);

  k_fill      <<<EDGES/256, 256, 0, stream>>>(ei, cnt);
  k_dinv      <<<N_TOT/256, 256, 0, stream>>>(cnt, dinv);
  k_adj       <<<EDGES/256, 256, 0, stream>>>(ei, dinv, adjf);
  k_adjcast   <<<4096, 256, 0, stream>>>(adjf, dinv, adjb);
  k_castT_lin1<<<dim3(KBIG/32, MLP_HID/32), 256, 0, stream>>>(l1w, l1wt); // after adjf dead
  k_cast_x    <<<4096, 256, 0, stream>>>(x, xb);
  k_castT_w   <<<128, 256, 0, stream>>>(W1, W2, w1t, w2t);

  gemm_xw_T   <<<dim3(N_TOT/64, 2), 256, 0, stream>>>(xb, w1t, hT);
  gemm_adj    <<<dim3(N_TOT/64, 2), 256, 0, stream>>>(adjb, hT, b1, hact);
  gemm_xw_T   <<<dim3(N_TOT/64, 2), 256, 0, stream>>>(hact, w2t, hT);
  gemm_adj    <<<dim3(N_TOT/64, 2), 256, 0, stream>>>(adjb, hT, b2, hact);

  gemm_lin1   <<<dim3(4, 8, 32), 256, 0, stream>>>(hact, l1wt, h3);
  k_lin2      <<<NGRAPH/4, 256, 0, stream>>>(h3, l1b, l2w, l2b, out);
}

// Round 3
// 174.802 us; speedup vs baseline: 1.4680x; 1.4680x over previous
//
#include <hip/hip_runtime.h>
#include <hip/hip_bf16.h>

#define N_TOT   32768
#define NUMNODE 128
#define NGRAPH  256
#define EDGES   524288
#define HDIM    128
#define MLP_HID 512
#define OUTDIM  10
#define KBIG    16384   // NUMNODE*HDIM

typedef __attribute__((ext_vector_type(8))) short  short8;   // 8 x bf16 bits
typedef __attribute__((ext_vector_type(4))) float  floatx4;  // MFMA accumulator
typedef unsigned short u16;

#define MFMA(a,b,c) __builtin_amdgcn_mfma_f32_16x16x32_bf16((a),(b),(c),0,0,0)

__device__ __forceinline__ u16 f2b(float f){
  union { __hip_bfloat16 h; u16 u; } cv; cv.h = __float2bfloat16(f); return cv.u;
}

// ---- global degree count (target side) ----
__global__ __launch_bounds__(256) void k_fill(const int* __restrict__ ei,
                                              int* __restrict__ cnt){
  int e = blockIdx.x*256 + threadIdx.x;
  atomicAdd(&cnt[ei[EDGES + e]], 1);
}

// ---- dinv = rsqrt(deg + self-loop) ----
__global__ __launch_bounds__(256) void k_dinv(const int* __restrict__ cnt,
                                              float* __restrict__ dinv){
  int i = blockIdx.x*256 + threadIdx.x;
  dinv[i] = rsqrtf((float)(cnt[i] + 1));
}

// ---- W1/W2 transpose+cast: w_t[n][k] = W[k][n] bf16 ----
__global__ __launch_bounds__(256) void k_castT_w(const float* __restrict__ W1,
                                                 const float* __restrict__ W2,
                                                 u16* __restrict__ w1t,
                                                 u16* __restrict__ w2t){
  int idx = blockIdx.x*256 + threadIdx.x;
  int sel = idx >> 14; int i = idx & 16383;
  int k = i >> 7, n = i & 127;
  const float* W = sel ? W2 : W1;
  u16* D = sel ? w2t : w1t;
  D[n*HDIM + k] = f2b(W[k*HDIM + n]);
}

// ---- lin1_w [16384][512] -> transposed bf16 [512][16384] ----
__global__ __launch_bounds__(256) void k_castT_lin1(const float* __restrict__ W,
                                                    u16* __restrict__ WT){
  __shared__ u16 tile[32][33];
  int k0 = blockIdx.x*32, n0 = blockIdx.y*32;
  int lx = threadIdx.x & 31, ly = threadIdx.x >> 5;
  #pragma unroll
  for (int i = 0; i < 4; ++i)
    tile[ly + i*8][lx] = f2b(W[(size_t)(k0 + ly + i*8)*MLP_HID + n0 + lx]);
  __syncthreads();
  #pragma unroll
  for (int i = 0; i < 4; ++i)
    WT[(size_t)(n0 + ly + i*8)*KBIG + k0 + lx] = tile[lx][ly + i*8];
}

// ==== fused per-graph GNN megakernel ====
// block = 1 graph, 512 threads (8 waves). 64 KB LDS.
// Phases: zero -> edge scatter (counts) -> normalize+cast adj (swizzled bf16)
//   -> GEMM1 (x@W1, A from global fp32, B=w1t global) -> hT to LDS
//   -> agg1 (adj@h + b1, relu) -> h1act LDS -> GEMM2 (B=w2t global) -> h2T LDS
//   -> agg2 (+b2, relu) -> hact global [node][feat] bf16.
// LDS rows are 16B chunks XOR-swizzled by (row&7) -> frag reads are 2-way max.
__global__ __launch_bounds__(512) void k_gnn(
    const float* __restrict__ x, const int* __restrict__ ei,
    const float* __restrict__ dinv,
    const u16* __restrict__ w1t, const u16* __restrict__ w2t,
    const float* __restrict__ b1, const float* __restrict__ b2,
    u16* __restrict__ hact)
{
  __shared__ char smem[65536];
  float* adjF = (float*)smem;               // [128][128] fp32 counts (phases 0-2)
  u16*   adjB = (u16*)smem;                 // [128][128] bf16 swizzled (32 KB)
  u16*   R1   = (u16*)(smem + 32768);       // hT / h1act / h2T / out staging
  int g = blockIdx.x, t = threadIdx.x;
  int wave = t>>6, lane = t&63, r = lane&15, q = lane>>4;
  int m0 = wave*16;

  // P0: zero 64 KB
  #pragma unroll
  for (int i=0;i<8;++i) ((float4*)smem)[t + i*512] = make_float4(0.f,0.f,0.f,0.f);
  __syncthreads();

  // P1: scatter edge counts (edges of graph g are contiguous: [g*2048, g*2048+2048))
  #pragma unroll
  for (int k=0;k<4;++k){
    int e = g*2048 + k*512 + t;
    int s = ei[e] & 127;
    int d = ei[EDGES + e] & 127;
    atomicAdd(&adjF[d*128 + s], 1.0f);
  }
  __syncthreads();

  // P2: normalize (dinv[d]*dinv[s]*count) + self-loop diag, cast bf16, swizzle-pack
  {
    int drow = t >> 2, scol = (t & 3)*32;
    float vdst = dinv[g*128 + drow];
    float ds[32], vals[32];
    #pragma unroll
    for (int i=0;i<8;++i)
      ((float4*)ds)[i] = *(const float4*)(dinv + g*128 + scol + i*4);
    #pragma unroll
    for (int i=0;i<32;++i){
      float v = adjF[drow*128 + scol + i] * vdst * ds[i];
      if (drow == scol + i) v += vdst*vdst;
      vals[i] = v;
    }
    __syncthreads();           // all adjF reads complete before overwrite
    #pragma unroll
    for (int cc=0;cc<4;++cc){
      int ch  = (scol >> 3) + cc;          // 16B chunk index 0..15
      int swz = ch ^ (drow & 7);
      short8 o;
      #pragma unroll
      for (int j=0;j<8;++j) o[j] = (short)f2b(vals[cc*8 + j]);
      *(short8*)(adjB + drow*128 + swz*8) = o;
    }
  }
  __syncthreads();

  // P3: GEMM1  h1 = x @ W1 ; write transposed hT[f][node] swizzled into R1
  floatx4 acc[8];
  #pragma unroll
  for (int i=0;i<8;++i) acc[i] = (floatx4){0.f,0.f,0.f,0.f};
  {
    const float* xg = x + ((size_t)(g*128 + m0 + r))*HDIM;
    #pragma unroll
    for (int ks=0;ks<4;++ks){
      float4 a0 = *(const float4*)(xg + ks*32 + q*8);
      float4 a1 = *(const float4*)(xg + ks*32 + q*8 + 4);
      short8 af;
      af[0]=(short)f2b(a0.x); af[1]=(short)f2b(a0.y); af[2]=(short)f2b(a0.z); af[3]=(short)f2b(a0.w);
      af[4]=(short)f2b(a1.x); af[5]=(short)f2b(a1.y); af[6]=(short)f2b(a1.z); af[7]=(short)f2b(a1.w);
      #pragma unroll
      for (int nt=0;nt<8;++nt){
        short8 bf = *(const short8*)(w1t + (nt*16+r)*HDIM + ks*32 + q*8);
        acc[nt] = MFMA(af, bf, acc[nt]);
      }
    }
  }
  #pragma unroll
  for (int nt=0;nt<8;++nt){
    int f = nt*16 + r;
    int c = 2*wave + (q>>1);               // m-chunk of this lane's 4 rows
    ushort4 o; o.x=f2b(acc[nt][0]); o.y=f2b(acc[nt][1]); o.z=f2b(acc[nt][2]); o.w=f2b(acc[nt][3]);
    *(ushort4*)(R1 + f*128 + (c ^ (f&7))*8 + (q&1)*4) = o;
  }
  __syncthreads();

  // P4: agg1 = adj @ h1 (+b1, relu) -> h1act [d][f] swizzled into R1
  #pragma unroll
  for (int i=0;i<8;++i) acc[i] = (floatx4){0.f,0.f,0.f,0.f};
  #pragma unroll
  for (int ks=0;ks<4;++ks){
    int ca = ks*4 + q;
    short8 af = *(const short8*)(adjB + (m0+r)*128 + (ca ^ (r&7))*8);
    #pragma unroll
    for (int nt=0;nt<8;++nt){
      short8 bf = *(const short8*)(R1 + (nt*16+r)*128 + (ca ^ (r&7))*8);
      acc[nt] = MFMA(af, bf, acc[nt]);
    }
  }
  {
    u16 hv[32];
    #pragma unroll
    for (int nt=0;nt<8;++nt){
      float bb = b1[nt*16 + r];
      #pragma unroll
      for (int rr=0;rr<4;++rr) hv[nt*4+rr] = f2b(fmaxf(acc[nt][rr] + bb, 0.f));
    }
    __syncthreads();                       // hT reads done
    #pragma unroll
    for (int nt=0;nt<8;++nt){
      int ch = 2*nt + (r>>3);              // f-chunk
      #pragma unroll
      for (int rr=0;rr<4;++rr){
        int d = m0 + q*4 + rr;
        R1[d*128 + (ch ^ (d&7))*8 + (r&7)] = hv[nt*4+rr];
      }
    }
  }
  __syncthreads();

  // P5: GEMM2  h2 = h1act @ W2 ; h2T swizzled into R1
  #pragma unroll
  for (int i=0;i<8;++i) acc[i] = (floatx4){0.f,0.f,0.f,0.f};
  #pragma unroll
  for (int ks=0;ks<4;++ks){
    int ca = ks*4 + q;
    short8 af = *(const short8*)(R1 + (m0+r)*128 + (ca ^ (r&7))*8);
    #pragma unroll
    for (int nt=0;nt<8;++nt){
      short8 bf = *(const short8*)(w2t + (nt*16+r)*HDIM + ks*32 + q*8);
      acc[nt] = MFMA(af, bf, acc[nt]);
    }
  }
  {
    ushort4 ho[8];
    #pragma unroll
    for (int nt=0;nt<8;++nt){
      ho[nt].x=f2b(acc[nt][0]); ho[nt].y=f2b(acc[nt][1]);
      ho[nt].z=f2b(acc[nt][2]); ho[nt].w=f2b(acc[nt][3]);
    }
    __syncthreads();                       // h1act reads done
    #pragma unroll
    for (int nt=0;nt<8;++nt){
      int f = nt*16 + r;
      int c = 2*wave + (q>>1);
      *(ushort4*)(R1 + f*128 + (c ^ (f&7))*8 + (q&1)*4) = ho[nt];
    }
  }
  __syncthreads();

  // P6: agg2 = adj @ h2 (+b2, relu) -> linear [d][f] in R1 -> global
  #pragma unroll
  for (int i=0;i<8;++i) acc[i] = (floatx4){0.f,0.f,0.f,0.f};
  #pragma unroll
  for (int ks=0;ks<4;++ks){
    int ca = ks*4 + q;
    short8 af = *(const short8*)(adjB + (m0+r)*128 + (ca ^ (r&7))*8);
    #pragma unroll
    for (int nt=0;nt<8;++nt){
      short8 bf = *(const short8*)(R1 + (nt*16+r)*128 + (ca ^ (r&7))*8);
      acc[nt] = MFMA(af, bf, acc[nt]);
    }
  }
  {
    u16 hv[32];
    #pragma unroll
    for (int nt=0;nt<8;++nt){
      float bb = b2[nt*16 + r];
      #pragma unroll
      for (int rr=0;rr<4;++rr) hv[nt*4+rr] = f2b(fmaxf(acc[nt][rr] + bb, 0.f));
    }
    __syncthreads();                       // h2T reads done
    #pragma unroll
    for (int nt=0;nt<8;++nt){
      int f = nt*16 + r;
      #pragma unroll
      for (int rr=0;rr<4;++rr){
        int d = m0 + q*4 + rr;
        R1[d*128 + f] = hv[nt*4+rr];       // linear, for vectorized copy-out
      }
    }
  }
  __syncthreads();
  u16* hg = hact + (size_t)g*KBIG;
  #pragma unroll
  for (int i=0;i<4;++i) ((int4*)hg)[t + i*512] = ((const int4*)R1)[t + i*512];
}

// ---- lin1: [256 x 16384] @ BT[512][16384]; LDS-staged tiles, swizzled;
//      split-K=8 -> fp32 partials P[8][256][512] (no atomics) ----
__global__ __launch_bounds__(256) void gemm_lin1(
    const u16* __restrict__ A, const u16* __restrict__ BT, float* __restrict__ P)
{
  __shared__ char smem[65536];
  u16* Al = (u16*)smem;            // [64][256] ushort, 16B chunks swizzled
  u16* Bl = (u16*)(smem + 32768);
  int t = threadIdx.x;
  int wave = t>>6, lane = t&63, r = lane&15, q = lane>>4;
  int m0 = blockIdx.x*64, n0 = blockIdx.y*64;
  size_t k0 = (size_t)blockIdx.z*2048;
  floatx4 acc[4];
  #pragma unroll
  for (int i=0;i<4;++i) acc[i] = (floatx4){0.f,0.f,0.f,0.f};
  int c = t & 31, rbase = t >> 5;

  for (int it=0; it<8; ++it){
    __syncthreads();
    size_t kk = k0 + it*256;
    #pragma unroll
    for (int rep=0;rep<8;++rep){
      int row = rep*8 + rbase;
      int4 va = *(const int4*)(A  + (size_t)(m0+row)*KBIG + kk + c*8);
      int4 vb = *(const int4*)(BT + (size_t)(n0+row)*KBIG + kk + c*8);
      int swz = c ^ (row & 7);
      *(int4*)(Al + row*256 + swz*8) = va;
      *(int4*)(Bl + row*256 + swz*8) = vb;
    }
    __syncthreads();
    #pragma unroll
    for (int ks=0;ks<8;++ks){
      int ca = (ks*4 + q) ^ (r & 7);
      short8 a = *(const short8*)(Al + (wave*16+r)*256 + ca*8);
      #pragma unroll
      for (int nt=0;nt<4;++nt){
        short8 b = *(const short8*)(Bl + (nt*16+r)*256 + ca*8);
        acc[nt] = MFMA(a, b, acc[nt]);
      }
    }
  }
  float* Pp = P + (size_t)blockIdx.z*131072;
  #pragma unroll
  for (int nt=0;nt<4;++nt)
    #pragma unroll
    for (int rr=0;rr<4;++rr)
      Pp[(size_t)(m0 + wave*16 + q*4 + rr)*MLP_HID + n0 + nt*16 + r] = acc[nt][rr];
}

// ---- lin2 fused: reduce 8 partial slices + b1 + relu, then @ [512x10] + b2 ----
__global__ __launch_bounds__(256) void k_lin2(const float* __restrict__ P,
                                              const float* __restrict__ b1l,
                                              const float* __restrict__ w2,
                                              const float* __restrict__ b2,
                                              float* __restrict__ out){
  int wave = threadIdx.x >> 6, lane = threadIdx.x & 63;
  int m = blockIdx.x*4 + wave;
  float hv[8];
  #pragma unroll
  for (int i=0;i<8;++i){
    int idx = lane + i*64;
    float s = b1l[idx];
    #pragma unroll
    for (int sl=0;sl<8;++sl) s += P[(size_t)sl*131072 + (size_t)m*MLP_HID + idx];
    hv[i] = fmaxf(s, 0.f);
  }
  #pragma unroll
  for (int j=0;j<OUTDIM;++j){
    float p = 0.f;
    #pragma unroll
    for (int i=0;i<8;++i) p += hv[i] * w2[(lane + i*64)*OUTDIM + j];
    #pragma unroll
    for (int off=32; off>0; off>>=1) p += __shfl_down(p, off);
    if (lane == 0) out[m*OUTDIM + j] = p + b2[j];
  }
}

extern "C" void kernel_launch(void* const* d_in, const int* in_sizes, int n_in,
                              void* d_out, int out_size, void* d_ws, size_t ws_size,
                              hipStream_t stream){
  const float* x   = (const float*)d_in[0];
  const int*   ei  = (const int*)d_in[1];
  const float* W1  = (const float*)d_in[3];
  const float* b1  = (const float*)d_in[4];
  const float* W2  = (const float*)d_in[5];
  const float* b2  = (const float*)d_in[6];
  const float* l1w = (const float*)d_in[7];
  const float* l1b = (const float*)d_in[8];
  const float* l2w = (const float*)d_in[9];
  const float* l2b = (const float*)d_in[10];
  float* out = (float*)d_out;

  char* ws = (char*)d_ws;
  int*   cnt  = (int*)  (ws + 0);          // 128 KB (memset)
  float* dinv = (float*)(ws + 131072);     // 128 KB
  u16*   w1t  = (u16*)  (ws + 262144);     // 32 KB
  u16*   w2t  = (u16*)  (ws + 294912);     // 32 KB
  u16*   l1wt = (u16*)  (ws + 327680);     // 16 MB
  u16*   hact = (u16*)  (ws + 17104896);   // 8 MB
  float* P    = (float*)(ws + 25493504);   // 4 MB (fully overwritten, no init)

  hipMemsetAsync(cnt, 0, 131072, stream);
  k_fill      <<<EDGES/256, 256, 0, stream>>>(ei, cnt);
  k_dinv      <<<N_TOT/256, 256, 0, stream>>>(cnt, dinv);
  k_castT_w   <<<128, 256, 0, stream>>>(W1, W2, w1t, w2t);
  k_castT_lin1<<<dim3(KBIG/32, MLP_HID/32), 256, 0, stream>>>(l1w, l1wt);

  k_gnn       <<<NGRAPH, 512, 0, stream>>>(x, ei, dinv, w1t, w2t, b1, b2, hact);

  gemm_lin1   <<<dim3(4, 8, 8), 256, 0, stream>>>(hact, l1wt, P);
  k_lin2      <<<NGRAPH/4, 256, 0, stream>>>(P, l1b, l2w, l2b, out);
}

// Round 4
// 157.637 us; speedup vs baseline: 1.6278x; 1.1089x over previous
//
#include <hip/hip_runtime.h>
#include <hip/hip_bf16.h>

#define N_TOT   32768
#define NUMNODE 128
#define NGRAPH  256
#define EDGES   524288
#define HDIM    128
#define MLP_HID 512
#define OUTDIM  10
#define KBIG    16384   // NUMNODE*HDIM

typedef __attribute__((ext_vector_type(8))) short  short8;   // 8 x bf16 bits
typedef __attribute__((ext_vector_type(4))) float  floatx4;  // MFMA accumulator
typedef unsigned short u16;
typedef unsigned int   u32;

#define MFMA(a,b,c) __builtin_amdgcn_mfma_f32_16x16x32_bf16((a),(b),(c),0,0,0)

__device__ __forceinline__ u16 f2b(float f){
  union { __hip_bfloat16 h; u16 u; } cv; cv.h = __float2bfloat16(f); return cv.u;
}

// ---- prep: W1/W2 transpose+cast (blocks 0..127) + zero h3 (blocks 128..255) ----
__global__ __launch_bounds__(256) void k_prep(const float* __restrict__ W1,
                                              const float* __restrict__ W2,
                                              u16* __restrict__ w1t,
                                              u16* __restrict__ w2t,
                                              float* __restrict__ h3){
  int b = blockIdx.x, t = threadIdx.x;
  if (b < 128){
    int idx = b*256 + t;                 // < 32768
    int sel = idx >> 14; int i = idx & 16383;
    int k = i >> 7, n = i & 127;
    const float* W = sel ? W2 : W1;
    u16* D = sel ? w2t : w1t;
    D[n*HDIM + k] = f2b(W[k*HDIM + n]);
  } else {
    ((int4*)h3)[(b-128)*256 + t] = make_int4(0,0,0,0);   // 32768 int4 = 512 KB
  }
}

// ==== fused per-graph GNN megakernel ====
// block = 1 graph, 512 threads (8 waves), 64 KB LDS.
// adjC/adjB: lower 32 KB (packed u16 counts -> in-place bf16 swizzled adj).
// R1: upper 32 KB (dinv stash, then hT / h1act / h2T / out staging).
__global__ __launch_bounds__(512) void k_gnn(
    const float* __restrict__ x, const int* __restrict__ ei,
    const u16* __restrict__ w1t, const u16* __restrict__ w2t,
    const float* __restrict__ b1, const float* __restrict__ b2,
    u16* __restrict__ hact)
{
  __shared__ char smem[65536];
  u32*   adjC  = (u32*)smem;                // [128][64] packed u16 counts
  u16*   adjB  = (u16*)smem;                // [128][128] bf16 swizzled (32 KB)
  u16*   R1    = (u16*)(smem + 32768);
  float* dinvL = (float*)(smem + 32768);    // 128 floats (dead before P3)
  int g = blockIdx.x, t = threadIdx.x;
  int wave = t>>6, lane = t&63, r = lane&15, q = lane>>4;
  int m0 = wave*16;

  // P0: zero lower 32 KB (counts)
  #pragma unroll
  for (int i=0;i<4;++i) ((int4*)smem)[t + i*512] = make_int4(0,0,0,0);
  __syncthreads();

  // P1: scatter edge counts, packed 2 per u32 (max 2048 < 65536, no overflow)
  #pragma unroll
  for (int k=0;k<4;++k){
    int e = g*2048 + k*512 + t;
    int s = ei[e] & 127;
    int d = ei[EDGES + e] & 127;
    atomicAdd(&adjC[d*64 + (s>>1)], 1u << (16*(s&1)));
  }
  __syncthreads();

  // P1b: in-degree row sums -> dinv = rsqrt(deg+1)
  {
    int drow = t >> 2, c0 = (t & 3)*16;
    u32 sum = 0;
    #pragma unroll
    for (int i=0;i<16;++i){
      u32 v = adjC[drow*64 + c0 + i];
      sum += (v & 0xffffu) + (v >> 16);
    }
    sum += __shfl_xor((int)sum, 1);
    sum += __shfl_xor((int)sum, 2);
    if ((t & 3) == 0) dinvL[drow] = rsqrtf((float)sum + 1.0f);
  }
  __syncthreads();

  // P2: normalize counts -> bf16 adjacency, in place, XOR-swizzled chunks.
  // Each thread reads only its own cells (read-all-then-write-all, same wave per row).
  {
    int drow = t >> 2, scol = (t & 3)*32;
    float vdst = dinvL[drow];
    float ds[32];
    #pragma unroll
    for (int i=0;i<8;++i)
      ((float4*)ds)[i] = *(const float4*)(dinvL + scol + i*4);
    float vals[32];
    #pragma unroll
    for (int i=0;i<16;++i){
      u32 v = adjC[drow*64 + (scol>>1) + i];
      vals[2*i]   = (float)(v & 0xffffu) * vdst * ds[2*i];
      vals[2*i+1] = (float)(v >> 16)     * vdst * ds[2*i+1];
    }
    #pragma unroll
    for (int i=0;i<32;++i) if (drow == scol + i) vals[i] += vdst*vdst;
    #pragma unroll
    for (int cc=0;cc<4;++cc){
      int ch  = (scol >> 3) + cc;
      int swz = ch ^ (drow & 7);
      short8 o;
      #pragma unroll
      for (int j=0;j<8;++j) o[j] = (short)f2b(vals[cc*8 + j]);
      *(short8*)(adjB + drow*128 + swz*8) = o;
    }
  }
  __syncthreads();

  // P3: GEMM1  h1 = x @ W1 ; write transposed hT[f][node] swizzled into R1
  floatx4 acc[8];
  #pragma unroll
  for (int i=0;i<8;++i) acc[i] = (floatx4){0.f,0.f,0.f,0.f};
  {
    const float* xg = x + ((size_t)(g*128 + m0 + r))*HDIM;
    #pragma unroll
    for (int ks=0;ks<4;++ks){
      float4 a0 = *(const float4*)(xg + ks*32 + q*8);
      float4 a1 = *(const float4*)(xg + ks*32 + q*8 + 4);
      short8 af;
      af[0]=(short)f2b(a0.x); af[1]=(short)f2b(a0.y); af[2]=(short)f2b(a0.z); af[3]=(short)f2b(a0.w);
      af[4]=(short)f2b(a1.x); af[5]=(short)f2b(a1.y); af[6]=(short)f2b(a1.z); af[7]=(short)f2b(a1.w);
      #pragma unroll
      for (int nt=0;nt<8;++nt){
        short8 bf = *(const short8*)(w1t + (nt*16+r)*HDIM + ks*32 + q*8);
        acc[nt] = MFMA(af, bf, acc[nt]);
      }
    }
  }
  #pragma unroll
  for (int nt=0;nt<8;++nt){
    int f = nt*16 + r;
    int c = 2*wave + (q>>1);
    ushort4 o; o.x=f2b(acc[nt][0]); o.y=f2b(acc[nt][1]); o.z=f2b(acc[nt][2]); o.w=f2b(acc[nt][3]);
    *(ushort4*)(R1 + f*128 + (c ^ (f&7))*8 + (q&1)*4) = o;
  }
  __syncthreads();

  // P4: agg1 = adj @ h1 (+b1, relu) -> h1act [d][f] swizzled into R1
  #pragma unroll
  for (int i=0;i<8;++i) acc[i] = (floatx4){0.f,0.f,0.f,0.f};
  #pragma unroll
  for (int ks=0;ks<4;++ks){
    int ca = ks*4 + q;
    short8 af = *(const short8*)(adjB + (m0+r)*128 + (ca ^ (r&7))*8);
    #pragma unroll
    for (int nt=0;nt<8;++nt){
      short8 bf = *(const short8*)(R1 + (nt*16+r)*128 + (ca ^ (r&7))*8);
      acc[nt] = MFMA(af, bf, acc[nt]);
    }
  }
  {
    u16 hv[32];
    #pragma unroll
    for (int nt=0;nt<8;++nt){
      float bb = b1[nt*16 + r];
      #pragma unroll
      for (int rr=0;rr<4;++rr) hv[nt*4+rr] = f2b(fmaxf(acc[nt][rr] + bb, 0.f));
    }
    __syncthreads();                       // hT reads done
    #pragma unroll
    for (int nt=0;nt<8;++nt){
      int ch = 2*nt + (r>>3);
      #pragma unroll
      for (int rr=0;rr<4;++rr){
        int d = m0 + q*4 + rr;
        R1[d*128 + (ch ^ (d&7))*8 + (r&7)] = hv[nt*4+rr];
      }
    }
  }
  __syncthreads();

  // P5: GEMM2  h2 = h1act @ W2 ; h2T swizzled into R1
  #pragma unroll
  for (int i=0;i<8;++i) acc[i] = (floatx4){0.f,0.f,0.f,0.f};
  #pragma unroll
  for (int ks=0;ks<4;++ks){
    int ca = ks*4 + q;
    short8 af = *(const short8*)(R1 + (m0+r)*128 + (ca ^ (r&7))*8);
    #pragma unroll
    for (int nt=0;nt<8;++nt){
      short8 bf = *(const short8*)(w2t + (nt*16+r)*HDIM + ks*32 + q*8);
      acc[nt] = MFMA(af, bf, acc[nt]);
    }
  }
  {
    ushort4 ho[8];
    #pragma unroll
    for (int nt=0;nt<8;++nt){
      ho[nt].x=f2b(acc[nt][0]); ho[nt].y=f2b(acc[nt][1]);
      ho[nt].z=f2b(acc[nt][2]); ho[nt].w=f2b(acc[nt][3]);
    }
    __syncthreads();                       // h1act reads done
    #pragma unroll
    for (int nt=0;nt<8;++nt){
      int f = nt*16 + r;
      int c = 2*wave + (q>>1);
      *(ushort4*)(R1 + f*128 + (c ^ (f&7))*8 + (q&1)*4) = ho[nt];
    }
  }
  __syncthreads();

  // P6: agg2 = adj @ h2 (+b2, relu) -> linear [d][f] in R1 -> global
  #pragma unroll
  for (int i=0;i<8;++i) acc[i] = (floatx4){0.f,0.f,0.f,0.f};
  #pragma unroll
  for (int ks=0;ks<4;++ks){
    int ca = ks*4 + q;
    short8 af = *(const short8*)(adjB + (m0+r)*128 + (ca ^ (r&7))*8);
    #pragma unroll
    for (int nt=0;nt<8;++nt){
      short8 bf = *(const short8*)(R1 + (nt*16+r)*128 + (ca ^ (r&7))*8);
      acc[nt] = MFMA(af, bf, acc[nt]);
    }
  }
  {
    u16 hv[32];
    #pragma unroll
    for (int nt=0;nt<8;++nt){
      float bb = b2[nt*16 + r];
      #pragma unroll
      for (int rr=0;rr<4;++rr) hv[nt*4+rr] = f2b(fmaxf(acc[nt][rr] + bb, 0.f));
    }
    __syncthreads();                       // h2T reads done
    #pragma unroll
    for (int nt=0;nt<8;++nt){
      int f = nt*16 + r;
      #pragma unroll
      for (int rr=0;rr<4;++rr){
        int d = m0 + q*4 + rr;
        R1[d*128 + f] = hv[nt*4+rr];
      }
    }
  }
  __syncthreads();
  u16* hg = hact + (size_t)g*KBIG;
  #pragma unroll
  for (int i=0;i<4;++i) ((int4*)hg)[t + i*512] = ((const int4*)R1)[t + i*512];
}

// ---- lin1: hact[256x16384]bf16 @ lin1_w[16384x512]fp32 (cast fused in staging)
//      tiles 128(M) x 64(N) x 128(K), split-K=16, atomicAdd into pre-zeroed h3 ----
__global__ __launch_bounds__(512) void gemm_lin1(
    const u16* __restrict__ A, const float* __restrict__ W, float* __restrict__ h3)
{
  __shared__ char smem[49152];
  u16* Al = (u16*)smem;            // [128][128] u16, 16B chunks XOR-swizzled
  u16* Bl = (u16*)(smem + 32768);  // [64][128]  u16, swizzled (W^T bf16)
  int t = threadIdx.x;
  int wave = t>>6, lane = t&63, r = lane&15, q = lane>>4;
  int m0 = blockIdx.x*128, n0 = blockIdx.y*64;
  floatx4 acc[4];
  #pragma unroll
  for (int i=0;i<4;++i) acc[i] = (floatx4){0.f,0.f,0.f,0.f};

  int arow_b = t >> 4, achk = t & 15;            // A staging: 32 rows/pass
  int bn = t & 63, bkb = (t >> 6)*16;            // B staging: n=lane, 16 k-rows/thread

  for (int it=0; it<8; ++it){
    __syncthreads();
    int kk = blockIdx.z*1024 + it*128;
    #pragma unroll
    for (int p=0;p<4;++p){
      int row = p*32 + arow_b;
      int4 va = *(const int4*)(A + (size_t)(m0+row)*KBIG + kk + achk*8);
      *(int4*)(Al + row*128 + (achk ^ (row&7))*8) = va;
    }
    #pragma unroll
    for (int cc=0;cc<2;++cc){
      short8 o;
      #pragma unroll
      for (int j=0;j<8;++j)
        o[j] = (short)f2b(W[(size_t)(kk + bkb + cc*8 + j)*MLP_HID + n0 + bn]);
      int ch = (bkb >> 3) + cc;
      *(short8*)(Bl + bn*128 + (ch ^ (bn&7))*8) = o;
    }
    __syncthreads();
    #pragma unroll
    for (int ks=0;ks<4;++ks){
      int ca = ks*4 + q;
      short8 a = *(const short8*)(Al + (wave*16+r)*128 + ((ca ^ (r&7)))*8);
      #pragma unroll
      for (int nt=0;nt<4;++nt){
        short8 b = *(const short8*)(Bl + (nt*16+r)*128 + ((ca ^ (r&7)))*8);
        acc[nt] = MFMA(a, b, acc[nt]);
      }
    }
  }
  #pragma unroll
  for (int nt=0;nt<4;++nt)
    #pragma unroll
    for (int rr=0;rr<4;++rr)
      atomicAdd(&h3[(size_t)(m0 + wave*16 + q*4 + rr)*MLP_HID + n0 + nt*16 + r],
                acc[nt][rr]);
}

// ---- lin2 fused: h3 + b1 relu, then @ [512x10] + b2 ----
__global__ __launch_bounds__(256) void k_lin2(const float* __restrict__ h3,
                                              const float* __restrict__ b1l,
                                              const float* __restrict__ w2,
                                              const float* __restrict__ b2,
                                              float* __restrict__ out){
  int wave = threadIdx.x >> 6, lane = threadIdx.x & 63;
  int m = blockIdx.x*4 + wave;
  float hv[8];
  #pragma unroll
  for (int i=0;i<8;++i)
    hv[i] = fmaxf(h3[(size_t)m*MLP_HID + lane + i*64] + b1l[lane + i*64], 0.f);
  #pragma unroll
  for (int j=0;j<OUTDIM;++j){
    float p = 0.f;
    #pragma unroll
    for (int i=0;i<8;++i) p += hv[i] * w2[(lane + i*64)*OUTDIM + j];
    #pragma unroll
    for (int off=32; off>0; off>>=1) p += __shfl_down(p, off);
    if (lane == 0) out[m*OUTDIM + j] = p + b2[j];
  }
}

extern "C" void kernel_launch(void* const* d_in, const int* in_sizes, int n_in,
                              void* d_out, int out_size, void* d_ws, size_t ws_size,
                              hipStream_t stream){
  const float* x   = (const float*)d_in[0];
  const int*   ei  = (const int*)d_in[1];
  const float* W1  = (const float*)d_in[3];
  const float* b1  = (const float*)d_in[4];
  const float* W2  = (const float*)d_in[5];
  const float* b2  = (const float*)d_in[6];
  const float* l1w = (const float*)d_in[7];
  const float* l1b = (const float*)d_in[8];
  const float* l2w = (const float*)d_in[9];
  const float* l2b = (const float*)d_in[10];
  float* out = (float*)d_out;

  char* ws = (char*)d_ws;
  u16*   w1t  = (u16*)  (ws + 0);          // 32 KB
  u16*   w2t  = (u16*)  (ws + 32768);      // 32 KB
  float* h3   = (float*)(ws + 65536);      // 512 KB (zeroed by k_prep)
  u16*   hact = (u16*)  (ws + 589824);     // 8 MB

  k_prep    <<<256, 256, 0, stream>>>(W1, W2, w1t, w2t, h3);
  k_gnn     <<<NGRAPH, 512, 0, stream>>>(x, ei, w1t, w2t, b1, b2, hact);
  gemm_lin1 <<<dim3(2, 8, 16), 512, 0, stream>>>(hact, l1w, h3);
  k_lin2    <<<NGRAPH/4, 256, 0, stream>>>(h3, l1b, l2w, l2b, out);
}

// Round 5
// 141.241 us; speedup vs baseline: 1.8168x; 1.1161x over previous
//
#include <hip/hip_runtime.h>
#include <hip/hip_bf16.h>

#define N_TOT   32768
#define NUMNODE 128
#define NGRAPH  256
#define EDGES   524288
#define HDIM    128
#define MLP_HID 512
#define OUTDIM  10
#define KBIG    16384   // NUMNODE*HDIM

typedef __attribute__((ext_vector_type(8))) short  short8;   // 8 x bf16 bits
typedef __attribute__((ext_vector_type(4))) float  floatx4;  // MFMA accumulator
typedef unsigned short u16;
typedef unsigned int   u32;

#define MFMA(a,b,c) __builtin_amdgcn_mfma_f32_16x16x32_bf16((a),(b),(c),0,0,0)

__device__ __forceinline__ u16 f2b(float f){
  union { __hip_bfloat16 h; u16 u; } cv; cv.h = __float2bfloat16(f); return cv.u;
}

// ==== fully self-contained per-graph GNN megakernel ====
// block = 1 graph, 512 threads (8 waves), 64 KB LDS.
// Lower 32 KB: adjC counts -> adjB bf16 swizzled -> (after P5) w2T.
// Upper 32 KB: w1T -> hT -> h1T -> amid -> out staging.
// Layer 2 uses associativity: h2 = relu((A@h1act)@W2 + b2).
// All LDS rows = 128 u16 = 16 chunks of 16B, chunk XOR-swizzled by (row&7).
__global__ __launch_bounds__(512) void k_gnn(
    const float* __restrict__ x, const int* __restrict__ ei,
    const float* __restrict__ W1, const float* __restrict__ W2,
    const float* __restrict__ b1, const float* __restrict__ b2,
    u16* __restrict__ hact)
{
  __shared__ char smem[65536];
  u32*   adjC  = (u32*)smem;                // [128][64] packed u16 counts
  u16*   adjB  = (u16*)smem;                // [128][128] bf16 swizzled
  u16*   WL    = (u16*)smem;                // w2T home (after P5)
  float* dinvF = (float*)smem;              // 128 floats (transient)
  u16*   R1    = (u16*)(smem + 32768);      // w1T / hT / h1T / amid / out
  int g = blockIdx.x, t = threadIdx.x;
  int wave = t>>6, lane = t&63, r = lane&15, q = lane>>4;
  int m0 = wave*16;

  // P0: zero lower 32 KB; stage w1T (transposed bf16, swizzled) into upper
  #pragma unroll
  for (int i=0;i<4;++i) ((int4*)smem)[t + i*512] = make_int4(0,0,0,0);
  #pragma unroll
  for (int rep=0;rep<32;++rep){
    int idx = rep*512 + t;                  // = k*128 + n (W1 flat)
    int n = idx & 127, k = idx >> 7;
    R1[n*128 + (((k>>3) ^ (n&7)))*8 + (k&7)] = f2b(W1[idx]);
  }
  __syncthreads();

  // P1: scatter edge counts, packed 2 per u32
  #pragma unroll
  for (int k=0;k<4;++k){
    int e = g*2048 + k*512 + t;
    int s = ei[e] & 127;
    int d = ei[EDGES + e] & 127;
    atomicAdd(&adjC[d*64 + (s>>1)], 1u << (16*(s&1)));
  }
  __syncthreads();

  // P2a: read own quarter-row counts -> regs; rowsum via shfl -> dinv_own
  int drow = t >> 2, c0q = (t & 3)*16, scol = (t & 3)*32;
  u32 cnts[16];
  float dinv_own;
  {
    u32 sum = 0;
    #pragma unroll
    for (int i=0;i<16;++i){
      cnts[i] = adjC[drow*64 + c0q + i];
      sum += (cnts[i] & 0xffffu) + (cnts[i] >> 16);
    }
    sum += __shfl_xor((int)sum, 1);
    sum += __shfl_xor((int)sum, 2);
    dinv_own = rsqrtf((float)sum + 1.0f);
  }
  __syncthreads();
  // P2b: publish dinv
  if ((t & 3) == 0) dinvF[drow] = dinv_own;
  __syncthreads();
  // P2c: read dinv row + 32 cols -> regs
  float vdst = dinvF[drow];
  float ds[32];
  #pragma unroll
  for (int i=0;i<8;++i)
    ((float4*)ds)[i] = *(const float4*)(dinvF + scol + i*4);
  __syncthreads();
  // P2d: normalize + self-loop diag, write adjB swizzled
  {
    float vals[32];
    #pragma unroll
    for (int i=0;i<16;++i){
      vals[2*i]   = (float)(cnts[i] & 0xffffu) * vdst * ds[2*i];
      vals[2*i+1] = (float)(cnts[i] >> 16)     * vdst * ds[2*i+1];
    }
    #pragma unroll
    for (int i=0;i<32;++i) if (drow == scol + i) vals[i] += vdst*vdst;
    #pragma unroll
    for (int cc=0;cc<4;++cc){
      int ch  = (scol >> 3) + cc;
      short8 o;
      #pragma unroll
      for (int j=0;j<8;++j) o[j] = (short)f2b(vals[cc*8 + j]);
      *(short8*)(adjB + drow*128 + (ch ^ (drow&7))*8) = o;
    }
  }
  // no barrier needed before P3 (P3 touches only upper LDS + global)

  // P3: GEMM1  h1 = x @ W1 (w1T from upper) -> hT [f][node] into upper
  floatx4 acc[8];
  #pragma unroll
  for (int i=0;i<8;++i) acc[i] = (floatx4){0.f,0.f,0.f,0.f};
  {
    const float* xg = x + ((size_t)(g*128 + m0 + r))*HDIM;
    #pragma unroll
    for (int ks=0;ks<4;++ks){
      float4 a0 = *(const float4*)(xg + ks*32 + q*8);
      float4 a1 = *(const float4*)(xg + ks*32 + q*8 + 4);
      short8 af;
      af[0]=(short)f2b(a0.x); af[1]=(short)f2b(a0.y); af[2]=(short)f2b(a0.z); af[3]=(short)f2b(a0.w);
      af[4]=(short)f2b(a1.x); af[5]=(short)f2b(a1.y); af[6]=(short)f2b(a1.z); af[7]=(short)f2b(a1.w);
      #pragma unroll
      for (int nt=0;nt<8;++nt){
        short8 bf = *(const short8*)(R1 + (nt*16+r)*128 + (((ks*4+q) ^ (r&7)))*8);
        acc[nt] = MFMA(af, bf, acc[nt]);
      }
    }
  }
  __syncthreads();                          // w1T reads done; adjB writes done
  #pragma unroll
  for (int nt=0;nt<8;++nt){
    int f = nt*16 + r;
    int c = 2*wave + (q>>1);
    ushort4 o; o.x=f2b(acc[nt][0]); o.y=f2b(acc[nt][1]); o.z=f2b(acc[nt][2]); o.w=f2b(acc[nt][3]);
    *(ushort4*)(R1 + f*128 + (c ^ (f&7))*8 + (q&1)*4) = o;
  }
  __syncthreads();

  // P4: agg1 = adj @ h1 (+b1, relu) -> h1T [f][node] (transposed write) upper
  #pragma unroll
  for (int i=0;i<8;++i) acc[i] = (floatx4){0.f,0.f,0.f,0.f};
  #pragma unroll
  for (int ks=0;ks<4;++ks){
    int ca = ks*4 + q;
    short8 af = *(const short8*)(adjB + (m0+r)*128 + ((ca ^ (r&7)))*8);
    #pragma unroll
    for (int nt=0;nt<8;++nt){
      short8 bf = *(const short8*)(R1 + (nt*16+r)*128 + ((ca ^ (r&7)))*8);
      acc[nt] = MFMA(af, bf, acc[nt]);
    }
  }
  {
    ushort4 ho[8];
    #pragma unroll
    for (int nt=0;nt<8;++nt){
      float bb = b1[nt*16 + r];
      ho[nt].x = f2b(fmaxf(acc[nt][0] + bb, 0.f));
      ho[nt].y = f2b(fmaxf(acc[nt][1] + bb, 0.f));
      ho[nt].z = f2b(fmaxf(acc[nt][2] + bb, 0.f));
      ho[nt].w = f2b(fmaxf(acc[nt][3] + bb, 0.f));
    }
    __syncthreads();                        // hT reads done
    #pragma unroll
    for (int nt=0;nt<8;++nt){
      int f = nt*16 + r;                    // col -> row of h1T
      int c = 2*wave + (q>>1);              // node chunk
      *(ushort4*)(R1 + f*128 + (c ^ (f&7))*8 + (q&1)*4) = ho[nt];
    }
  }
  __syncthreads();

  // P5: amid = adj @ h1act -> [d][f] A-layout swizzled upper; stage w2T lower
  #pragma unroll
  for (int i=0;i<8;++i) acc[i] = (floatx4){0.f,0.f,0.f,0.f};
  #pragma unroll
  for (int ks=0;ks<4;++ks){
    int ca = ks*4 + q;
    short8 af = *(const short8*)(adjB + (m0+r)*128 + ((ca ^ (r&7)))*8);
    #pragma unroll
    for (int nt=0;nt<8;++nt){
      short8 bf = *(const short8*)(R1 + (nt*16+r)*128 + ((ca ^ (r&7)))*8);
      acc[nt] = MFMA(af, bf, acc[nt]);
    }
  }
  {
    u16 hv[32];
    #pragma unroll
    for (int nt=0;nt<8;++nt)
      #pragma unroll
      for (int rr=0;rr<4;++rr) hv[nt*4+rr] = f2b(acc[nt][rr]);
    __syncthreads();                        // adjB + h1T reads done
    #pragma unroll
    for (int rep=0;rep<32;++rep){           // w2T -> lower (overwrite adjB)
      int idx = rep*512 + t;
      int n = idx & 127, k = idx >> 7;
      WL[n*128 + (((k>>3) ^ (n&7)))*8 + (k&7)] = f2b(W2[idx]);
    }
    #pragma unroll
    for (int nt=0;nt<8;++nt){
      int ch = 2*nt + (r>>3);
      #pragma unroll
      for (int rr=0;rr<4;++rr){
        int d = m0 + q*4 + rr;
        R1[d*128 + (ch ^ (d&7))*8 + (r&7)] = hv[nt*4+rr];
      }
    }
  }
  __syncthreads();

  // P6: h2 = relu(amid @ W2 + b2) -> out [d][f] -> global
  #pragma unroll
  for (int i=0;i<8;++i) acc[i] = (floatx4){0.f,0.f,0.f,0.f};
  #pragma unroll
  for (int ks=0;ks<4;++ks){
    int ca = ks*4 + q;
    short8 af = *(const short8*)(R1 + (m0+r)*128 + ((ca ^ (r&7)))*8);
    #pragma unroll
    for (int nt=0;nt<8;++nt){
      short8 bf = *(const short8*)(WL + (nt*16+r)*128 + ((ca ^ (r&7)))*8);
      acc[nt] = MFMA(af, bf, acc[nt]);
    }
  }
  {
    u16 hv[32];
    #pragma unroll
    for (int nt=0;nt<8;++nt){
      float bb = b2[nt*16 + r];
      #pragma unroll
      for (int rr=0;rr<4;++rr) hv[nt*4+rr] = f2b(fmaxf(acc[nt][rr] + bb, 0.f));
    }
    __syncthreads();                        // amid reads done
    #pragma unroll
    for (int nt=0;nt<8;++nt){
      int f = nt*16 + r;
      #pragma unroll
      for (int rr=0;rr<4;++rr){
        int d = m0 + q*4 + rr;
        R1[d*128 + f] = hv[nt*4+rr];        // linear for vectorized copy-out
      }
    }
  }
  __syncthreads();
  u16* hg = hact + (size_t)g*KBIG;
  #pragma unroll
  for (int i=0;i<4;++i) ((int4*)hg)[t + i*512] = ((const int4*)R1)[t + i*512];
}

// ---- lin1: hact[256x16384]bf16 @ lin1_w[16384x512]fp32 (cast in staging).
//      Full-M tile: 256(M) x 64(N) x BK=64, 64 k-slices -> fp32 partials. ----
__global__ __launch_bounds__(512) void gemm_lin1(
    const u16* __restrict__ A, const float* __restrict__ W, float* __restrict__ P)
{
  __shared__ u16 Al[256*64];     // 32 KB: row m, 8 chunks XOR-swizzled
  __shared__ u16 Bl[64*64];      // 8 KB:  row n, 8 chunks XOR-swizzled
  int t = threadIdx.x;
  int wave = t>>6, lane = t&63, r = lane&15, q = lane>>4;
  int n0 = blockIdx.x*64;
  int kbase = blockIdx.y*256;    // 64 slices x 256 K each
  floatx4 acc[2][4];
  #pragma unroll
  for (int i=0;i<2;++i)
    #pragma unroll
    for (int j=0;j<4;++j) acc[i][j] = (floatx4){0.f,0.f,0.f,0.f};

  for (int it=0; it<4; ++it){
    __syncthreads();
    int kk = kbase + it*64;
    #pragma unroll
    for (int p=0;p<4;++p){                  // A: 256 rows x 64 k
      int idx = p*512 + t;
      int row = idx >> 3, ch = idx & 7;
      int4 va = *(const int4*)(A + (size_t)row*KBIG + kk + ch*8);
      *(int4*)(Al + row*64 + ((ch ^ (row&7)))*8) = va;
    }
    #pragma unroll
    for (int h=0;h<2;++h){                  // B: W[kk..kk+63][n0..n0+63] -> Bl[n][k]
      int i = h*512 + t;
      int k = i >> 4, n4 = i & 15;
      float4 w = *(const float4*)(W + (size_t)(kk + k)*MLP_HID + n0 + n4*4);
      #pragma unroll
      for (int j=0;j<4;++j){
        int n = n4*4 + j;
        Bl[n*64 + (((k>>3) ^ (n&7)))*8 + (k&7)] = f2b(j==0?w.x:j==1?w.y:j==2?w.z:w.w);
      }
    }
    __syncthreads();
    #pragma unroll
    for (int ks=0;ks<2;++ks){
      int ca = ks*4 + q;
      short8 a0 = *(const short8*)(Al + (wave*32      + r)*64 + ((ca ^ (r&7)))*8);
      short8 a1 = *(const short8*)(Al + (wave*32 + 16 + r)*64 + ((ca ^ (r&7)))*8);
      #pragma unroll
      for (int nt=0;nt<4;++nt){
        short8 b = *(const short8*)(Bl + (nt*16+r)*64 + ((ca ^ (r&7)))*8);
        acc[0][nt] = MFMA(a0, b, acc[0][nt]);
        acc[1][nt] = MFMA(a1, b, acc[1][nt]);
      }
    }
  }
  float* Pp = P + (size_t)blockIdx.y*131072;
  #pragma unroll
  for (int mm=0;mm<2;++mm)
    #pragma unroll
    for (int nt=0;nt<4;++nt)
      #pragma unroll
      for (int rr=0;rr<4;++rr)
        Pp[(size_t)(wave*32 + mm*16 + q*4 + rr)*MLP_HID + n0 + nt*16 + r] = acc[mm][nt][rr];
}

// ---- lin2: reduce 64 partial slices + b1, relu, then @ [512x10] + b2 ----
__global__ __launch_bounds__(256) void k_lin2(const float* __restrict__ P,
                                              const float* __restrict__ b1l,
                                              const float* __restrict__ w2,
                                              const float* __restrict__ b2,
                                              float* __restrict__ out){
  __shared__ float hs[MLP_HID];
  int g = blockIdx.x, t = threadIdx.x;
  #pragma unroll
  for (int c2=0;c2<2;++c2){
    int c = c2*256 + t;
    float s = b1l[c];
    #pragma unroll 8
    for (int sl=0;sl<64;++sl) s += P[(size_t)sl*131072 + (size_t)g*MLP_HID + c];
    hs[c] = fmaxf(s, 0.f);
  }
  __syncthreads();
  int wave = t >> 6, lane = t & 63;
  for (int j = wave; j < OUTDIM; j += 4){
    float p = 0.f;
    #pragma unroll
    for (int i=0;i<8;++i) p += hs[lane + i*64] * w2[(lane + i*64)*OUTDIM + j];
    #pragma unroll
    for (int off=32; off>0; off>>=1) p += __shfl_down(p, off);
    if (lane == 0) out[g*OUTDIM + j] = p + b2[j];
  }
}

extern "C" void kernel_launch(void* const* d_in, const int* in_sizes, int n_in,
                              void* d_out, int out_size, void* d_ws, size_t ws_size,
                              hipStream_t stream){
  const float* x   = (const float*)d_in[0];
  const int*   ei  = (const int*)d_in[1];
  const float* W1  = (const float*)d_in[3];
  const float* b1  = (const float*)d_in[4];
  const float* W2  = (const float*)d_in[5];
  const float* b2  = (const float*)d_in[6];
  const float* l1w = (const float*)d_in[7];
  const float* l1b = (const float*)d_in[8];
  const float* l2w = (const float*)d_in[9];
  const float* l2b = (const float*)d_in[10];
  float* out = (float*)d_out;

  char* ws = (char*)d_ws;
  u16*   hact = (u16*)  (ws + 0);          // 8 MB
  float* P    = (float*)(ws + 8388608);    // 32 MB partials (fully overwritten)

  k_gnn     <<<NGRAPH, 512, 0, stream>>>(x, ei, W1, W2, b1, b2, hact);
  gemm_lin1 <<<dim3(8, 64), 512, 0, stream>>>(hact, l1w, P);
  k_lin2    <<<NGRAPH, 256, 0, stream>>>(P, l1b, l2w, l2b, out);
}